// Round 6
// baseline (1286487.207 us; speedup 1.0000x reference)
//
#include <hip/hip_runtime.h>
#include <hip/hip_bf16.h>
#include <math.h>

#define HID    512
#define BATCH  256
#define TLEN   512
#define FUT    16
#define NSTEP  (TLEN + FUT)   // 528
#define NGRP   16             // batch groups
#define WPG    16             // workgroups per group (512-thread WGs)
#define BPG    16             // batch per group
#define UPW    32             // hidden units per WG
#define NR     128            // gate rows per WG (4 gates * UPW)

// workspace byte offsets (all 256-aligned)
#define OFF_W0   0u           // packed Whh0 slices  [16][128][512]  bf16 = 2 MB
#define OFF_W1   2097152u     // packed [Wih1|Whh1]  [16][128][1024] bf16 = 4 MB
#define OFF_CA   6291456u     // activations [grp(16)][p][half][b(16)][gran][u8] bf16 = 1 MB
#define OFF_XF   7340032u     // feedback outs [FUT+1][256] f32
#define OFF_WI   7357440u     // Wih0 col packed [16][128] f32
#define OFF_B0   7365632u     // bih0+bhh0 packed [16][128] f32
#define OFF_B1   7373824u     // bih1+bhh1 packed [16][128] f32
#define OFF_BAR  7382016u     // 16 groups * 32 uints: [0..15]=flags, [16..31]=probe tokens
#define OFF_XT   7384064u     // x transposed [TLEN][BATCH] f32 = 512 KB

typedef __bf16 bf16x8 __attribute__((ext_vector_type(8)));
typedef float  f32x4  __attribute__((ext_vector_type(4)));

__device__ __forceinline__ float sigf(float v)      { return 1.f / (1.f + __expf(-v)); }
__device__ __forceinline__ float tanh_fast(float v) { return 2.f / (1.f + __expf(-2.f * v)) - 1.f; }

// ---- LLC-scope (safe anywhere) exchange ops --------------------------------
__device__ __forceinline__ void store_short_llc(void* p, unsigned short v) {
    asm volatile("global_store_short %0, %1, off sc0 sc1"
                 :: "v"(p), "v"((unsigned)v) : "memory");
}
__device__ __forceinline__ void gl2lds16_llc(const void* g, void* l) {
    __builtin_amdgcn_global_load_lds(
        (const __attribute__((address_space(1))) void*)g,
        (__attribute__((address_space(3))) void*)l, 16, 0, 17);   // sc0|sc1
}
// ---- L2-scope ops (XCD-local fast path; enabled only by group consensus) ---
__device__ __forceinline__ void store_short_l2(void* p, unsigned short v) {
    asm volatile("global_store_short %0, %1, off sc0"
                 :: "v"(p), "v"((unsigned)v) : "memory");
}
__device__ __forceinline__ void gl2lds16_l2(const void* g, void* l) {
    __builtin_amdgcn_global_load_lds(
        (const __attribute__((address_space(1))) void*)g,
        (__attribute__((address_space(3))) void*)l, 16, 0, 1);    // sc0 only
}
__device__ __forceinline__ void store_u32_l2(unsigned* p, unsigned v) {
    asm volatile("global_store_dword %0, %1, off sc0" :: "v"(p), "v"(v) : "memory");
}
__device__ __forceinline__ unsigned load_u32_l2(const unsigned* p) {
    unsigned v;
    asm volatile("global_load_dword %0, %1, off sc0\n\t"
                 "s_waitcnt vmcnt(0)" : "=v"(v) : "v"(p) : "memory");
    return v;
}

// flag-array barrier with OWN-FLAG SKIP.
// Fast path (l2fast): poll the 64B flags line via sc0 global_load_lds DMA into
// LDS scratch -- the SAME primitive the (r4-proven) data reload uses, so it is
// HW-proven to observe other CUs' sc0 stores, and it structurally cannot hit a
// warm L1 line (r5's failure mode: sc0 global_load spin hit stale L1 forever,
// burning the fallback budget on every barrier -> timeout). Writer dual-stores
// (sc0 for L2 readers, agent for fallback). Bounded spin (2^14 sleeps ~0.4ms)
// then agent-scope polling -> hang structurally impossible.
__device__ __forceinline__ void flag_barrier(unsigned* flags, volatile unsigned* scr,
                                             int m, unsigned phase, bool l2fast) {
    __builtin_amdgcn_s_waitcnt(0);
    __syncthreads();
    if (threadIdx.x == 0) {
        if (l2fast) store_u32_l2(&flags[m], phase);
        __hip_atomic_store(&flags[m], phase, __ATOMIC_RELAXED, __HIP_MEMORY_SCOPE_AGENT);
    }
    if (threadIdx.x < 64) {
        const int lane = threadIdx.x;
        const bool active = (lane < WPG) && (lane != m);
        bool fast = l2fast;
        int spins = 0;
        for (;;) {
            unsigned f = phase;
            if (fast) {
                if (lane < 4)
                    gl2lds16_l2((const char*)flags + lane * 16, (void*)(scr + lane * 4));
                __builtin_amdgcn_s_waitcnt(0);        // DMA -> LDS complete
                __builtin_amdgcn_sched_barrier(0);    // no hoisting of the LDS read
                if (active) f = scr[lane];
            } else if (active) {
                f = __hip_atomic_load(&flags[lane], __ATOMIC_RELAXED, __HIP_MEMORY_SCOPE_AGENT);
            }
            if (__ballot(f >= phase) == ~0ull) break;
            __builtin_amdgcn_s_sleep(1);
            if (++spins > (1 << 14)) fast = false;    // hang-proof LLC fallback
        }
    }
    __syncthreads();
}

__global__ void lstm_init(char* __restrict__ ws, float* __restrict__ out,
                          const float* __restrict__ blin)
{
    float bl = blin[0];
    int tid = blockIdx.x * blockDim.x + threadIdx.x;
    int stride = gridDim.x * blockDim.x;
    uint4* ca = (uint4*)(ws + OFF_CA);
    for (int i = tid; i < 65536; i += stride) ca[i] = make_uint4(0u, 0u, 0u, 0u);
    float* xf = (float*)(ws + OFF_XF);
    for (int i = tid; i < (FUT + 1) * BATCH; i += stride) xf[i] = bl;
    unsigned* bar = (unsigned*)(ws + OFF_BAR);
    for (int i = tid; i < NGRP * 32; i += stride) bar[i] = 0u;   // flags + tokens
    for (int i = tid; i < BATCH * NSTEP; i += stride) out[i] = bl;
}

__global__ void lstm_pack(char* __restrict__ ws,
    const float* __restrict__ x,
    const float* __restrict__ Wih0, const float* __restrict__ Whh0,
    const float* __restrict__ bih0, const float* __restrict__ bhh0,
    const float* __restrict__ Wih1, const float* __restrict__ Whh1,
    const float* __restrict__ bih1, const float* __restrict__ bhh1)
{
    int tid = blockIdx.x * blockDim.x + threadIdx.x;
    int stride = gridDim.x * blockDim.x;

    // W0: [16][128][512], row r of slice m -> global row (r>>5)*HID + m*32 + (r&31)
    __hip_bfloat16* W0p = (__hip_bfloat16*)(ws + OFF_W0);
    for (int i = tid; i < 16 * 128 * 512; i += stride) {
        int k = i & 511, r = (i >> 9) & 127, m = i >> 16;
        int row = (r >> 5) * HID + m * UPW + (r & 31);
        W0p[i] = __float2bfloat16(Whh0[(size_t)row * HID + k]);
    }
    __hip_bfloat16* W1p = (__hip_bfloat16*)(ws + OFF_W1);
    for (int i = tid; i < 16 * 128 * 1024; i += stride) {
        int k = i & 1023, r = (i >> 10) & 127, m = i >> 17;
        int row = (r >> 5) * HID + m * UPW + (r & 31);
        float v = (k < 512) ? Wih1[(size_t)row * HID + k] : Whh1[(size_t)row * HID + (k - 512)];
        W1p[i] = __float2bfloat16(v);
    }
    float* wi = (float*)(ws + OFF_WI);
    float* b0 = (float*)(ws + OFF_B0);
    float* b1 = (float*)(ws + OFF_B1);
    for (int i = tid; i < 16 * 128; i += stride) {
        int r = i & 127, m = i >> 7;
        int row = (r >> 5) * HID + m * UPW + (r & 31);
        wi[i] = Wih0[row];                  // IN = 1
        b0[i] = bih0[row] + bhh0[row];
        b1[i] = bih1[row] + bhh1[row];
    }
    float* xT = (float*)(ws + OFF_XT);      // [T][B] for coalesced step reads
    for (int i = tid; i < TLEN * BATCH; i += stride) {
        int t = i >> 8, b = i & 255;
        xT[i] = x[(size_t)b * TLEN + t];
    }
}

// Pin exactly 2 waves/EU (8 waves/CU = one 512-thread WG per CU).
__global__ __attribute__((amdgpu_flat_work_group_size(512, 512),
                          amdgpu_waves_per_eu(2, 2)))
void lstm_persist(
    const float* __restrict__ wlin,
    float* __restrict__ out, char* __restrict__ ws)
{
    const int tid  = threadIdx.x;
    const int lane = tid & 63;
    const int wave = tid >> 6;         // 0..7
    // One 512-thread WG per CU (grid=256). g=bid&15 keeps group g's members
    // at bid ≡ g (mod 8) -> XCD-local under the round-robin placement model;
    // the functional probe + group consensus below VERIFY before enabling.
    const int g    = blockIdx.x & 15;  // group 0..15
    const int m    = blockIdx.x >> 4;  // member within group: unit slice 0..15
    const int bbase = g * BPG;

    // As: 16 rows x 2048B; row r holds [h0 gran 0..63 | h1 gran 0..63],
    // content granule c stored at granule (c + r) & 63 of its half (swizzle).
    __shared__ __attribute__((aligned(16))) __hip_bfloat16 As[16 * 1024];
    // SINGLE K-split partial buffer shared by L0/L1 phases (two would exceed
    // the 64KB/WG LDS limit). [khalf][batch][gate-row], stride 140 (2-way).
    // Sharing hazards: L0wr->sync1->ew0rd->flag_barrier(syncthreads)->sync2
    // ->L1wr->sync3->ew1rd->tailsync->next L0wr. Every pair barrier-ordered.
    __shared__ float gp[2][16][140];
    __shared__ __attribute__((aligned(16))) unsigned flagScr[16];  // barrier DMA scratch
    __shared__ int l2okS;
    char* AsB = (char*)As;

    // zero As (t=0 reads h0prev=0, h1prev=0 from it)
    {
        int* az = (int*)As;
        for (int i = tid; i < (16 * 1024 * 2) / 4; i += 512) az[i] = 0;
    }

    const float* wis = (const float*)(ws + OFF_WI) + m * NR;
    const float* b0s = (const float*)(ws + OFF_B0) + m * NR;
    const float* b1s = (const float*)(ws + OFF_B1) + m * NR;
    // CA layout per group (64KB): [parity][half][b(16)][gran(64)][u8] bf16
    char* CAg = ws + OFF_CA + (size_t)g * 65536;
    float* xfeed = (float*)(ws + OFF_XF);
    const float* xT = (const float*)(ws + OFF_XT);
    unsigned* flags = (unsigned*)(ws + OFF_BAR) + g * 32;
    unsigned* tok   = flags + 16;      // probe token slots (zeroed by init)

    const int fl = lane & 15;          // n sub-index in fragment
    const int fq = lane >> 4;          // quad (k sub-chunk)
    const int kh = wave >> 2;          // K-half this wave reduces (0/1)
    const int wq = wave & 3;           // row-quad: wave owns row-tiles 2wq, 2wq+1
    const int us  = tid & 31;          // unit within slice (elementwise), 0..31
    const int b0r = tid >> 5;          // batch row 0..15

    const float wl0 = wlin[m * UPW + us];
    float wiR[4], b0R[4], b1R[4];
#pragma unroll
    for (int q = 0; q < 4; ++q) {
        wiR[q] = wis[q * 32 + us];
        b0R[q] = b0s[q * 32 + us];
        b1R[q] = b1s[q * 32 + us];
    }
    float c00 = 0.f, c10 = 0.f;        // cell state regs (layer 0 / layer 1)

    // publish byte offset (within a half): content granule c = 4m + (us>>3),
    // row b -> granule (c+b)&63, plus (us&7)*2 within the 16B granule.
    const int cgr  = 4 * m + (us >> 3);
    const int pub0 = b0r * 1024 + (((cgr + b0r) & 63) << 4) + (us & 7) * 2;

    // ---- load this wave's weight slice: 2 row-tiles x half-K (48 bf16x8
    //      frags/lane). 2-way K-split: each LDS A-read feeds 2 MFMAs.
    const bf16x8* W0base = (const bf16x8*)(ws + OFF_W0 + (size_t)m * NR * 512 * 2);
    const bf16x8* W1base = (const bf16x8*)(ws + OFF_W1 + (size_t)m * NR * 1024 * 2);
    bf16x8 w0f[2][8], w1f[2][16];
#pragma unroll
    for (int rt = 0; rt < 2; ++rt) {
        const int row = (wq * 2 + rt) * 16 + fl;
#pragma unroll
        for (int j = 0; j < 8; ++j)
            w0f[rt][j] = W0base[(size_t)row * 64 + (kh * 8 + j) * 4 + fq];
#pragma unroll
        for (int j = 0; j < 16; ++j)
            w1f[rt][j] = W1base[(size_t)row * 128 + (kh * 16 + j) * 4 + fq];
    }

    __syncthreads();  // As zeroed before use

    // ---- functional coherence self-test (sc0 stores seen by sc0 loads?),
    //      two token rounds, then GROUP CONSENSUS so all 16 WGs agree on one
    //      protocol (fixes the mixed-protocol hole: a lone dissenting WG
    //      would otherwise publish at a scope others don't read).
    unsigned phase = 0;
    {
        if (tid == 0) store_u32_l2(&tok[m], 0xA5000000u | (unsigned)m);
        ++phase; flag_barrier(flags, flagScr, m, phase, false);   // agent-only
        if (tid < 64) {
            const bool act = (tid < WPG);
            unsigned v = act ? load_u32_l2(&tok[tid]) : 0u;
            int eq = act ? (v == (0xA5000000u | (unsigned)tid)) : 1;
            unsigned long long bal = __ballot(eq);
            if (tid == 0) l2okS = (bal == ~0ull) ? 1 : 0;
        }
        __syncthreads();
        if (tid == 0) store_u32_l2(&tok[m], 0x5A110000u | (unsigned)m);
        ++phase; flag_barrier(flags, flagScr, m, phase, false);
        if (tid < 64) {
            const bool act = (tid < WPG);
            unsigned v = act ? load_u32_l2(&tok[tid]) : 0u;
            int eq = act ? (v == (0x5A110000u | (unsigned)tid)) : 1;
            unsigned long long bal = __ballot(eq);
            if (tid == 0 && bal != ~0ull) l2okS = 0;
        }
        __syncthreads();
        // consensus round: encode local verdict in the flag value (3=fail,
        // 4=ok) of an agent-scope barrier round; AND across all 16 members.
        const unsigned myv = 3u + (unsigned)l2okS;
        __builtin_amdgcn_s_waitcnt(0);
        __syncthreads();
        if (tid == 0)
            __hip_atomic_store(&flags[m], myv, __ATOMIC_RELAXED, __HIP_MEMORY_SCOPE_AGENT);
        if (tid < 64) {
            const bool act = (tid < WPG) && (tid != m);
            for (;;) {
                unsigned f = 3u;
                if (act) f = __hip_atomic_load(&flags[tid], __ATOMIC_RELAXED, __HIP_MEMORY_SCOPE_AGENT);
                if (__ballot(f >= 3u) == ~0ull) break;
                __builtin_amdgcn_s_sleep(1);
            }
            // flags now final (single store per WG this round): AND verdicts
            unsigned v = 4u;
            if (tid < WPG)
                v = (tid == m) ? myv
                               : __hip_atomic_load(&flags[tid], __ATOMIC_RELAXED, __HIP_MEMORY_SCOPE_AGENT);
            unsigned long long bal = __ballot(v >= 4u);
            if (tid == 0) l2okS = (bal == ~0ull) ? 1 : 0;
        }
        __syncthreads();
        phase = 4;   // flags hold 3 or 4; main-loop phases start at 5
    }
    const bool l2ok = (l2okS != 0);

    const bf16x8* Asv = (const bf16x8*)As;   // 16 rows x 128 granules

    for (int t = 0; t < NSTEP; ++t) {
        const int p = t & 1;
        char* CAp = CAg + p * 32768;          // this step's parity (h0/h1 writes)
        char* CAq = CAg + (1 - p) * 32768;    // previous parity (h1prev reads)

        float xv0;
        if (t < TLEN) {
            xv0 = xT[t * BATCH + bbase + b0r];
        } else {
            xv0 = xfeed[(t - TLEN) * BATCH + bbase + b0r];
        }

        // ---------------- layer 0 GEMM from LDS (h0prev, swizzled half 0)
        // rows (2wq..2wq+1)*16, K in [kh*256, kh*256+256): 8 A-reads, 16 MFMAs.
        f32x4 acc0 = {0.f, 0.f, 0.f, 0.f};
        f32x4 acc1 = {0.f, 0.f, 0.f, 0.f};
#pragma unroll
        for (int j = 0; j < 8; ++j) {
            const int c = kh * 32 + j * 4 + fq;
            bf16x8 a0 = Asv[fl * 128 + ((c + fl) & 63)];
            acc0 = __builtin_amdgcn_mfma_f32_16x16x32_bf16(a0, w0f[0][j], acc0, 0, 0, 0);
            acc1 = __builtin_amdgcn_mfma_f32_16x16x32_bf16(a0, w0f[1][j], acc1, 0, 0, 0);
        }
#pragma unroll
        for (int i = 0; i < 4; ++i) {     // C layout: m = quad*4+reg, n = lane&15
            gp[kh][fq * 4 + i][(wq * 2 + 0) * 16 + fl] = acc0[i];
            gp[kh][fq * 4 + i][(wq * 2 + 1) * 16 + fl] = acc1[i];
        }
        __syncthreads();               // sync1: gp writes -> ew0 reads

        // ---------------- layer 0 elementwise (sum K-half partials), publish h0
        {
            float gi = gp[0][b0r][us]      + gp[1][b0r][us]      + b0R[0] + xv0 * wiR[0];
            float gf = gp[0][b0r][32 + us] + gp[1][b0r][32 + us] + b0R[1] + xv0 * wiR[1];
            float gg = gp[0][b0r][64 + us] + gp[1][b0r][64 + us] + b0R[2] + xv0 * wiR[2];
            float go = gp[0][b0r][96 + us] + gp[1][b0r][96 + us] + b0R[3] + xv0 * wiR[3];
            c00 = sigf(gf) * c00 + sigf(gi) * tanh_fast(gg);
            __hip_bfloat16 h = __float2bfloat16(sigf(go) * tanh_fast(c00));
            if (l2ok) store_short_l2 (CAp + pub0, *(unsigned short*)&h);
            else      store_short_llc(CAp + pub0, *(unsigned short*)&h);
        }

        ++phase;
        flag_barrier(flags, flagScr, m, phase, l2ok);  // h0(t)+h1(t-1) -> all WGs
        // (its internal __syncthreads also orders ew0's gp reads before the
        //  layer-1 gp writes below.)

        // ---------------- stage [h0new | h1prev] -> LDS As
        // fully-contiguous 1KB DMA per (row, half): global gran == LDS gran
        {
#pragma unroll
            for (int ci = 0; ci < 2; ++ci) {
                int b = wave * 2 + ci;
                if (l2ok) {
                    gl2lds16_l2 (CAp + b * 1024 + lane * 16,
                                 AsB + b * 2048 + lane * 16);            // h0 new
                    gl2lds16_l2 (CAq + 16384 + b * 1024 + lane * 16,
                                 AsB + b * 2048 + 1024 + lane * 16);     // h1 prev
                } else {
                    gl2lds16_llc(CAp + b * 1024 + lane * 16,
                                 AsB + b * 2048 + lane * 16);
                    gl2lds16_llc(CAq + 16384 + b * 1024 + lane * 16,
                                 AsB + b * 2048 + 1024 + lane * 16);
                }
            }
            __builtin_amdgcn_s_waitcnt(0);
            __syncthreads();             // sync2: DMA -> L1 reads
        }

        // ---------------- layer 1 GEMM: K=1024 over [h0new | h1prev], K-split
        // kh=0 -> h0 half (granules 0..63), kh=1 -> h1 half (granules 64..127)
        acc0 = (f32x4){0.f, 0.f, 0.f, 0.f};
        acc1 = (f32x4){0.f, 0.f, 0.f, 0.f};
#pragma unroll
        for (int j = 0; j < 16; ++j) {
            const int c = j * 4 + fq;
            bf16x8 a0 = Asv[fl * 128 + kh * 64 + ((c + fl) & 63)];
            acc0 = __builtin_amdgcn_mfma_f32_16x16x32_bf16(a0, w1f[0][j], acc0, 0, 0, 0);
            acc1 = __builtin_amdgcn_mfma_f32_16x16x32_bf16(a0, w1f[1][j], acc1, 0, 0, 0);
        }
#pragma unroll
        for (int i = 0; i < 4; ++i) {
            gp[kh][fq * 4 + i][(wq * 2 + 0) * 16 + fl] = acc0[i];
            gp[kh][fq * 4 + i][(wq * 2 + 1) * 16 + fl] = acc1[i];
        }
        __syncthreads();               // sync3: gp writes -> ew1 reads

        // ---------------- layer 1 elementwise + OUT=1 linear, publish h1
        {
            float gi = gp[0][b0r][us]      + gp[1][b0r][us]      + b1R[0];
            float gf = gp[0][b0r][32 + us] + gp[1][b0r][32 + us] + b1R[1];
            float gg = gp[0][b0r][64 + us] + gp[1][b0r][64 + us] + b1R[2];
            float go = gp[0][b0r][96 + us] + gp[1][b0r][96 + us] + b1R[3];
            c10 = sigf(gf) * c10 + sigf(gi) * tanh_fast(gg);
            float h = sigf(go) * tanh_fast(c10);
            __hip_bfloat16 hb = __float2bfloat16(h);
            if (l2ok) store_short_l2 (CAp + 16384 + pub0, *(unsigned short*)&hb);
            else      store_short_llc(CAp + 16384 + pub0, *(unsigned short*)&hb);
            float po = wl0 * h;
#pragma unroll
            for (int off = 1; off < 32; off <<= 1) po += __shfl_xor(po, off, 64);
            if (us == 0) {
                atomicAdd(&out[(size_t)(bbase + b0r) * NSTEP + t], po);
                if (t >= TLEN - 1)
                    atomicAdd(&xfeed[(t - (TLEN - 1)) * BATCH + bbase + b0r], po);
            }
        }

        // Tail ordering: ew1's gp reads must finish before next iteration's
        // L0 gp writes. FUT region gets it from the flag_barrier (which also
        // orders xfeed atomics -> next step's feedback reads); main region
        // needs one cheap intra-WG sync.
        if (t >= TLEN - 1) {
            ++phase;
            flag_barrier(flags, flagScr, m, phase, l2ok);
        } else {
            __syncthreads();
        }
    }
}

extern "C" void kernel_launch(void* const* d_in, const int* in_sizes, int n_in,
                              void* d_out, int out_size, void* d_ws, size_t ws_size,
                              hipStream_t stream)
{
    const float* x    = (const float*)d_in[0];
    const float* Wih0 = (const float*)d_in[1];
    const float* Whh0 = (const float*)d_in[2];
    const float* bih0 = (const float*)d_in[3];
    const float* bhh0 = (const float*)d_in[4];
    const float* Wih1 = (const float*)d_in[5];
    const float* Whh1 = (const float*)d_in[6];
    const float* bih1 = (const float*)d_in[7];
    const float* bhh1 = (const float*)d_in[8];
    const float* Wlin = (const float*)d_in[9];
    const float* blin = (const float*)d_in[10];
    float* out = (float*)d_out;
    char* ws = (char*)d_ws;

    hipLaunchKernelGGL(lstm_init, dim3(256), dim3(256), 0, stream, ws, out, blin);
    hipLaunchKernelGGL(lstm_pack, dim3(512), dim3(256), 0, stream,
                       ws, x, Wih0, Whh0, bih0, bhh0, Wih1, Whh1, bih1, bhh1);
    hipLaunchKernelGGL(lstm_persist, dim3(256), dim3(512), 0, stream, Wlin, out, ws);
}

// Round 7
// 1992.751 us; speedup vs baseline: 645.5836x; 645.5836x over previous
//
#include <hip/hip_runtime.h>
#include <hip/hip_bf16.h>
#include <math.h>

#define HID    512
#define BATCH  256
#define TLEN   512
#define FUT    16
#define NSTEP  (TLEN + FUT)   // 528
#define NGRP   16             // batch groups
#define WPG    16             // workgroups per group (512-thread WGs)
#define BPG    16             // batch per group
#define UPW    32             // hidden units per WG
#define NR     128            // gate rows per WG (4 gates * UPW)

// workspace byte offsets (all 256-aligned)
#define OFF_W0   0u           // packed Whh0 slices  [16][128][512]  bf16 = 2 MB
#define OFF_W1   2097152u     // packed [Wih1|Whh1]  [16][128][1024] bf16 = 4 MB
#define OFF_CA   6291456u     // activations [grp(16)][p][half][b(16)][gran][u8] bf16 = 1 MB
#define OFF_XF   7340032u     // feedback outs [FUT+1][256] f32
#define OFF_WI   7357440u     // Wih0 col packed [16][128] f32
#define OFF_B0   7365632u     // bih0+bhh0 packed [16][128] f32
#define OFF_B1   7373824u     // bih1+bhh1 packed [16][128] f32
#define OFF_BAR  7382016u     // 16 groups * 32 uints: [0..15]=flags, [16..31]=probe tokens
#define OFF_XT   7384064u     // x transposed [TLEN][BATCH] f32 = 512 KB

typedef __bf16 bf16x8 __attribute__((ext_vector_type(8)));
typedef float  f32x4  __attribute__((ext_vector_type(4)));

__device__ __forceinline__ float sigf(float v)      { return 1.f / (1.f + __expf(-v)); }
__device__ __forceinline__ float tanh_fast(float v) { return 2.f / (1.f + __expf(-2.f * v)) - 1.f; }

// ---- LLC-scope (safe anywhere) exchange ops --------------------------------
__device__ __forceinline__ void store_short_llc(void* p, unsigned short v) {
    asm volatile("global_store_short %0, %1, off sc0 sc1"
                 :: "v"(p), "v"((unsigned)v) : "memory");
}
__device__ __forceinline__ void gl2lds16_llc(const void* g, void* l) {
    __builtin_amdgcn_global_load_lds(
        (const __attribute__((address_space(1))) void*)g,
        (__attribute__((address_space(3))) void*)l, 16, 0, 17);   // sc0|sc1
}
// ---- L2-scope DATA ops (XCD-local fast path; enabled only if the runtime
//      coherence self-test passes). SESSION RULE (r2/r5/r6 failures): flags /
//      spin-polling NEVER use L2 scope -- sc0 flag polls do not observe
//      remote updates (stale L1 for global_load spins; DMA polls blind too).
//      Only bulk data (publish stores + staging DMA reloads) rides sc0. -----
__device__ __forceinline__ void store_short_l2(void* p, unsigned short v) {
    asm volatile("global_store_short %0, %1, off sc0"
                 :: "v"(p), "v"((unsigned)v) : "memory");
}
__device__ __forceinline__ void gl2lds16_l2(const void* g, void* l) {
    __builtin_amdgcn_global_load_lds(
        (const __attribute__((address_space(1))) void*)g,
        (__attribute__((address_space(3))) void*)l, 16, 0, 1);    // sc0 only
}
__device__ __forceinline__ void store_u32_l2(unsigned* p, unsigned v) {
    asm volatile("global_store_dword %0, %1, off sc0" :: "v"(p), "v"(v) : "memory");
}
__device__ __forceinline__ unsigned load_u32_l2(const unsigned* p) {
    unsigned v;
    asm volatile("global_load_dword %0, %1, off sc0\n\t"
                 "s_waitcnt vmcnt(0)" : "=v"(v) : "v"(p) : "memory");
    return v;
}

// flag-array barrier with OWN-FLAG SKIP. Flags are ALWAYS agent-scope (LLC)
// -- the r0/r4-proven protocol; hang-impossible regardless of placement.
// r7 tweak: first few polls back-to-back (the ~600cy LLC load latency already
// paces the loop), engage s_sleep only after that -> slightly lower detection
// latency at zero protocol risk.
__device__ __forceinline__ void flag_barrier(unsigned* flags, int m, unsigned phase) {
    __builtin_amdgcn_s_waitcnt(0);
    __syncthreads();
    if (threadIdx.x == 0)
        __hip_atomic_store(&flags[m], phase, __ATOMIC_RELAXED, __HIP_MEMORY_SCOPE_AGENT);
    if (threadIdx.x < 64) {
        const int lane = threadIdx.x;
        const bool active = (lane < WPG) && (lane != m);
        int it = 0;
        for (;;) {
            unsigned f = phase;
            if (active)
                f = __hip_atomic_load(&flags[lane], __ATOMIC_RELAXED, __HIP_MEMORY_SCOPE_AGENT);
            if (__ballot(f >= phase) == ~0ull) break;
            if (++it > 4) __builtin_amdgcn_s_sleep(1);
        }
    }
    __syncthreads();
}

__global__ void lstm_init(char* __restrict__ ws, float* __restrict__ out,
                          const float* __restrict__ blin)
{
    float bl = blin[0];
    int tid = blockIdx.x * blockDim.x + threadIdx.x;
    int stride = gridDim.x * blockDim.x;
    uint4* ca = (uint4*)(ws + OFF_CA);
    for (int i = tid; i < 65536; i += stride) ca[i] = make_uint4(0u, 0u, 0u, 0u);
    float* xf = (float*)(ws + OFF_XF);
    for (int i = tid; i < (FUT + 1) * BATCH; i += stride) xf[i] = bl;
    unsigned* bar = (unsigned*)(ws + OFF_BAR);
    for (int i = tid; i < NGRP * 32; i += stride) bar[i] = 0u;   // flags + tokens
    for (int i = tid; i < BATCH * NSTEP; i += stride) out[i] = bl;
}

__global__ void lstm_pack(char* __restrict__ ws,
    const float* __restrict__ x,
    const float* __restrict__ Wih0, const float* __restrict__ Whh0,
    const float* __restrict__ bih0, const float* __restrict__ bhh0,
    const float* __restrict__ Wih1, const float* __restrict__ Whh1,
    const float* __restrict__ bih1, const float* __restrict__ bhh1)
{
    int tid = blockIdx.x * blockDim.x + threadIdx.x;
    int stride = gridDim.x * blockDim.x;

    // W0: [16][128][512], row r of slice m -> global row (r>>5)*HID + m*32 + (r&31)
    __hip_bfloat16* W0p = (__hip_bfloat16*)(ws + OFF_W0);
    for (int i = tid; i < 16 * 128 * 512; i += stride) {
        int k = i & 511, r = (i >> 9) & 127, m = i >> 16;
        int row = (r >> 5) * HID + m * UPW + (r & 31);
        W0p[i] = __float2bfloat16(Whh0[(size_t)row * HID + k]);
    }
    __hip_bfloat16* W1p = (__hip_bfloat16*)(ws + OFF_W1);
    for (int i = tid; i < 16 * 128 * 1024; i += stride) {
        int k = i & 1023, r = (i >> 10) & 127, m = i >> 17;
        int row = (r >> 5) * HID + m * UPW + (r & 31);
        float v = (k < 512) ? Wih1[(size_t)row * HID + k] : Whh1[(size_t)row * HID + (k - 512)];
        W1p[i] = __float2bfloat16(v);
    }
    float* wi = (float*)(ws + OFF_WI);
    float* b0 = (float*)(ws + OFF_B0);
    float* b1 = (float*)(ws + OFF_B1);
    for (int i = tid; i < 16 * 128; i += stride) {
        int r = i & 127, m = i >> 7;
        int row = (r >> 5) * HID + m * UPW + (r & 31);
        wi[i] = Wih0[row];                  // IN = 1
        b0[i] = bih0[row] + bhh0[row];
        b1[i] = bih1[row] + bhh1[row];
    }
    float* xT = (float*)(ws + OFF_XT);      // [T][B] for coalesced step reads
    for (int i = tid; i < TLEN * BATCH; i += stride) {
        int t = i >> 8, b = i & 255;
        xT[i] = x[(size_t)b * TLEN + t];
    }
}

// Pin exactly 2 waves/EU (8 waves/CU = one 512-thread WG per CU).
__global__ __attribute__((amdgpu_flat_work_group_size(512, 512),
                          amdgpu_waves_per_eu(2, 2)))
void lstm_persist(
    const float* __restrict__ wlin,
    float* __restrict__ out, char* __restrict__ ws)
{
    const int tid  = threadIdx.x;
    const int lane = tid & 63;
    const int wave = tid >> 6;         // 0..7
    // One 512-thread WG per CU (grid=256). g=bid&15 keeps group g's members
    // at bid ≡ g (mod 8) -> XCD-local under the round-robin placement model;
    // the functional probe below VERIFIES this before enabling the fast path.
    const int g    = blockIdx.x & 15;  // group 0..15
    const int m    = blockIdx.x >> 4;  // member within group: unit slice 0..15
    const int bbase = g * BPG;

    // As: 16 rows x 2048B; row r holds [h0 gran 0..63 | h1 gran 0..63],
    // content granule c stored at granule (c + r) & 63 of its half (swizzle).
    __shared__ __attribute__((aligned(16))) __hip_bfloat16 As[16 * 1024];
    // SINGLE K-split partial buffer shared by L0/L1 phases (two would exceed
    // the 64KB/WG LDS limit). [khalf][batch][gate-row], stride 140 (2-way).
    // Sharing hazards: L0wr->sync1->ew0rd->flag_barrier(syncthreads)->sync2
    // ->L1wr->sync3->ew1rd->tailsync->next L0wr. Every pair barrier-ordered.
    __shared__ float gp[2][16][140];
    __shared__ int l2okS;
    char* AsB = (char*)As;

    // zero As (t=0 reads h0prev=0, h1prev=0 from it)
    {
        int* az = (int*)As;
        for (int i = tid; i < (16 * 1024 * 2) / 4; i += 512) az[i] = 0;
    }

    const float* wis = (const float*)(ws + OFF_WI) + m * NR;
    const float* b0s = (const float*)(ws + OFF_B0) + m * NR;
    const float* b1s = (const float*)(ws + OFF_B1) + m * NR;
    // CA layout per group (64KB): [parity][half][b(16)][gran(64)][u8] bf16
    char* CAg = ws + OFF_CA + (size_t)g * 65536;
    float* xfeed = (float*)(ws + OFF_XF);
    const float* xT = (const float*)(ws + OFF_XT);
    unsigned* flags = (unsigned*)(ws + OFF_BAR) + g * 32;
    unsigned* tok   = flags + 16;      // probe token slots (zeroed by init)

    const int fl = lane & 15;          // n sub-index in fragment
    const int fq = lane >> 4;          // quad (k sub-chunk)
    const int kh = wave >> 2;          // K-half this wave reduces (0/1)
    const int wq = wave & 3;           // row-quad: wave owns row-tiles 2wq, 2wq+1
    const int us  = tid & 31;          // unit within slice (elementwise), 0..31
    const int b0r = tid >> 5;          // batch row 0..15

    const float wl0 = wlin[m * UPW + us];
    float wiR[4], b0R[4], b1R[4];
#pragma unroll
    for (int q = 0; q < 4; ++q) {
        wiR[q] = wis[q * 32 + us];
        b0R[q] = b0s[q * 32 + us];
        b1R[q] = b1s[q * 32 + us];
    }
    float c00 = 0.f, c10 = 0.f;        // cell state regs (layer 0 / layer 1)

    // publish byte offset (within a half): content granule c = 4m + (us>>3),
    // row b -> granule (c+b)&63, plus (us&7)*2 within the 16B granule.
    const int cgr  = 4 * m + (us >> 3);
    const int pub0 = b0r * 1024 + (((cgr + b0r) & 63) << 4) + (us & 7) * 2;

    // ---- load this wave's weight slice: 2 row-tiles x half-K (48 bf16x8
    //      frags/lane). 2-way K-split: each LDS A-read feeds 2 MFMAs.
    const bf16x8* W0base = (const bf16x8*)(ws + OFF_W0 + (size_t)m * NR * 512 * 2);
    const bf16x8* W1base = (const bf16x8*)(ws + OFF_W1 + (size_t)m * NR * 1024 * 2);
    bf16x8 w0f[2][8], w1f[2][16];
#pragma unroll
    for (int rt = 0; rt < 2; ++rt) {
        const int row = (wq * 2 + rt) * 16 + fl;
#pragma unroll
        for (int j = 0; j < 8; ++j)
            w0f[rt][j] = W0base[(size_t)row * 64 + (kh * 8 + j) * 4 + fq];
#pragma unroll
        for (int j = 0; j < 16; ++j)
            w1f[rt][j] = W1base[(size_t)row * 128 + (kh * 16 + j) * 4 + fq];
    }

    __syncthreads();  // As zeroed before use

    // ---- functional coherence self-test: can sc0-only (L2-scope) stores by
    //      ANY member be read by sc0-only loads of EVERY member? Two rounds
    //      with different tokens so a line cached stale from round A fails
    //      round B (cross-XCD case). Probe barriers are agent-only -> cannot
    //      hang; worst case l2ok=0 -> proven LLC data path. Note verdicts
    //      cannot mix across members: sc0 visibility is symmetric, so any
    //      cross-XCD member hides its token from ALL members -> all fail.
    unsigned phase = 0;
    {
        if (tid == 0) store_u32_l2(&tok[m], 0xA5000000u | (unsigned)m);
        ++phase; flag_barrier(flags, m, phase);   // drains token store first
        if (tid < 64) {
            const bool act = (tid < WPG);
            unsigned v = act ? load_u32_l2(&tok[tid]) : 0u;
            int eq = act ? (v == (0xA5000000u | (unsigned)tid)) : 1;
            unsigned long long bal = __ballot(eq);
            if (tid == 0) l2okS = (bal == ~0ull) ? 1 : 0;
        }
        __syncthreads();
        if (tid == 0) store_u32_l2(&tok[m], 0x5A110000u | (unsigned)m);
        ++phase; flag_barrier(flags, m, phase);
        if (tid < 64) {
            const bool act = (tid < WPG);
            unsigned v = act ? load_u32_l2(&tok[tid]) : 0u;
            int eq = act ? (v == (0x5A110000u | (unsigned)tid)) : 1;
            unsigned long long bal = __ballot(eq);
            if (tid == 0 && bal != ~0ull) l2okS = 0;
        }
        __syncthreads();
    }
    const bool l2ok = (l2okS != 0);

    const bf16x8* Asv = (const bf16x8*)As;   // 16 rows x 128 granules

    for (int t = 0; t < NSTEP; ++t) {
        const int p = t & 1;
        char* CAp = CAg + p * 32768;          // this step's parity (h0/h1 writes)
        char* CAq = CAg + (1 - p) * 32768;    // previous parity (h1prev reads)

        float xv0;
        if (t < TLEN) {
            xv0 = xT[t * BATCH + bbase + b0r];
        } else {
            xv0 = xfeed[(t - TLEN) * BATCH + bbase + b0r];
        }

        // ---------------- layer 0 GEMM from LDS (h0prev, swizzled half 0)
        // rows (2wq..2wq+1)*16, K in [kh*256, kh*256+256): 8 A-reads, 16 MFMAs.
        f32x4 acc0 = {0.f, 0.f, 0.f, 0.f};
        f32x4 acc1 = {0.f, 0.f, 0.f, 0.f};
#pragma unroll
        for (int j = 0; j < 8; ++j) {
            const int c = kh * 32 + j * 4 + fq;
            bf16x8 a0 = Asv[fl * 128 + ((c + fl) & 63)];
            acc0 = __builtin_amdgcn_mfma_f32_16x16x32_bf16(a0, w0f[0][j], acc0, 0, 0, 0);
            acc1 = __builtin_amdgcn_mfma_f32_16x16x32_bf16(a0, w0f[1][j], acc1, 0, 0, 0);
        }
#pragma unroll
        for (int i = 0; i < 4; ++i) {     // C layout: m = quad*4+reg, n = lane&15
            gp[kh][fq * 4 + i][(wq * 2 + 0) * 16 + fl] = acc0[i];
            gp[kh][fq * 4 + i][(wq * 2 + 1) * 16 + fl] = acc1[i];
        }
        __syncthreads();               // sync1: gp writes -> ew0 reads

        // ---------------- layer 0 elementwise (sum K-half partials), publish h0
        {
            float gi = gp[0][b0r][us]      + gp[1][b0r][us]      + b0R[0] + xv0 * wiR[0];
            float gf = gp[0][b0r][32 + us] + gp[1][b0r][32 + us] + b0R[1] + xv0 * wiR[1];
            float gg = gp[0][b0r][64 + us] + gp[1][b0r][64 + us] + b0R[2] + xv0 * wiR[2];
            float go = gp[0][b0r][96 + us] + gp[1][b0r][96 + us] + b0R[3] + xv0 * wiR[3];
            c00 = sigf(gf) * c00 + sigf(gi) * tanh_fast(gg);
            __hip_bfloat16 h = __float2bfloat16(sigf(go) * tanh_fast(c00));
            if (l2ok) store_short_l2 (CAp + pub0, *(unsigned short*)&h);
            else      store_short_llc(CAp + pub0, *(unsigned short*)&h);
        }

        ++phase;
        flag_barrier(flags, m, phase);   // h0(t) + h1(t-1) publish -> all WGs
        // (its internal __syncthreads also orders ew0's gp reads before the
        //  layer-1 gp writes below.)

        // ---------------- stage [h0new | h1prev] -> LDS As
        // fully-contiguous 1KB DMA per (row, half): global gran == LDS gran
        {
#pragma unroll
            for (int ci = 0; ci < 2; ++ci) {
                int b = wave * 2 + ci;
                if (l2ok) {
                    gl2lds16_l2 (CAp + b * 1024 + lane * 16,
                                 AsB + b * 2048 + lane * 16);            // h0 new
                    gl2lds16_l2 (CAq + 16384 + b * 1024 + lane * 16,
                                 AsB + b * 2048 + 1024 + lane * 16);     // h1 prev
                } else {
                    gl2lds16_llc(CAp + b * 1024 + lane * 16,
                                 AsB + b * 2048 + lane * 16);
                    gl2lds16_llc(CAq + 16384 + b * 1024 + lane * 16,
                                 AsB + b * 2048 + 1024 + lane * 16);
                }
            }
            __builtin_amdgcn_s_waitcnt(0);
            __syncthreads();             // sync2: DMA -> L1 reads
        }

        // ---------------- layer 1 GEMM: K=1024 over [h0new | h1prev], K-split
        // kh=0 -> h0 half (granules 0..63), kh=1 -> h1 half (granules 64..127)
        acc0 = (f32x4){0.f, 0.f, 0.f, 0.f};
        acc1 = (f32x4){0.f, 0.f, 0.f, 0.f};
#pragma unroll
        for (int j = 0; j < 16; ++j) {
            const int c = j * 4 + fq;
            bf16x8 a0 = Asv[fl * 128 + kh * 64 + ((c + fl) & 63)];
            acc0 = __builtin_amdgcn_mfma_f32_16x16x32_bf16(a0, w1f[0][j], acc0, 0, 0, 0);
            acc1 = __builtin_amdgcn_mfma_f32_16x16x32_bf16(a0, w1f[1][j], acc1, 0, 0, 0);
        }
#pragma unroll
        for (int i = 0; i < 4; ++i) {
            gp[kh][fq * 4 + i][(wq * 2 + 0) * 16 + fl] = acc0[i];
            gp[kh][fq * 4 + i][(wq * 2 + 1) * 16 + fl] = acc1[i];
        }
        __syncthreads();               // sync3: gp writes -> ew1 reads

        // ---------------- layer 1 elementwise + OUT=1 linear, publish h1
        {
            float gi = gp[0][b0r][us]      + gp[1][b0r][us]      + b1R[0];
            float gf = gp[0][b0r][32 + us] + gp[1][b0r][32 + us] + b1R[1];
            float gg = gp[0][b0r][64 + us] + gp[1][b0r][64 + us] + b1R[2];
            float go = gp[0][b0r][96 + us] + gp[1][b0r][96 + us] + b1R[3];
            c10 = sigf(gf) * c10 + sigf(gi) * tanh_fast(gg);
            float h = sigf(go) * tanh_fast(c10);
            __hip_bfloat16 hb = __float2bfloat16(h);
            if (l2ok) store_short_l2 (CAp + 16384 + pub0, *(unsigned short*)&hb);
            else      store_short_llc(CAp + 16384 + pub0, *(unsigned short*)&hb);
            float po = wl0 * h;
#pragma unroll
            for (int off = 1; off < 32; off <<= 1) po += __shfl_xor(po, off, 64);
            if (us == 0) {
                atomicAdd(&out[(size_t)(bbase + b0r) * NSTEP + t], po);
                if (t >= TLEN - 1)
                    atomicAdd(&xfeed[(t - (TLEN - 1)) * BATCH + bbase + b0r], po);
            }
        }

        // Tail ordering: ew1's gp reads must finish before next iteration's
        // L0 gp writes. FUT region gets it from the flag_barrier (which also
        // orders xfeed atomics -> next step's feedback reads); main region
        // needs one cheap intra-WG sync.
        if (t >= TLEN - 1) {
            ++phase;
            flag_barrier(flags, m, phase);
        } else {
            __syncthreads();
        }
    }
}

extern "C" void kernel_launch(void* const* d_in, const int* in_sizes, int n_in,
                              void* d_out, int out_size, void* d_ws, size_t ws_size,
                              hipStream_t stream)
{
    const float* x    = (const float*)d_in[0];
    const float* Wih0 = (const float*)d_in[1];
    const float* Whh0 = (const float*)d_in[2];
    const float* bih0 = (const float*)d_in[3];
    const float* bhh0 = (const float*)d_in[4];
    const float* Wih1 = (const float*)d_in[5];
    const float* Whh1 = (const float*)d_in[6];
    const float* bih1 = (const float*)d_in[7];
    const float* bhh1 = (const float*)d_in[8];
    const float* Wlin = (const float*)d_in[9];
    const float* blin = (const float*)d_in[10];
    float* out = (float*)d_out;
    char* ws = (char*)d_ws;

    hipLaunchKernelGGL(lstm_init, dim3(256), dim3(256), 0, stream, ws, out, blin);
    hipLaunchKernelGGL(lstm_pack, dim3(512), dim3(256), 0, stream,
                       ws, x, Wih0, Whh0, bih0, bhh0, Wih1, Whh1, bih1, bhh1);
    hipLaunchKernelGGL(lstm_persist, dim3(256), dim3(512), 0, stream, Wlin, out, ws);
}